// Round 15
// baseline (63.189 us; speedup 1.0000x reference)
//
#include <hip/hip_runtime.h>
#include <math.h>

#define BB 32
#define TT 8192
#define CCH 128
#define OO 64
#define DD 288
#define NFREQ 12
#define NIJ 144

typedef _Float16 v8h __attribute__((ext_vector_type(8)));
typedef float f32x4 __attribute__((ext_vector_type(4)));

// ---------------- K1f: fourier emb + scores + softmax -> fragH, fused ----------------
#define IJ_CHUNK 36
#define EMB_LD 129

__global__ __launch_bounds__(256) void k1f_frag(const float* __restrict__ pos,
                                                const float* __restrict__ heads,
                                                uint4* __restrict__ fragH) {
    __shared__ float smem[2 * IJ_CHUNK * EMB_LD];   // 9288 floats = 37 KB
    float* cos_s = smem;
    float* sin_s = smem + IJ_CHUNK * EMB_LD;

    const int b = blockIdx.x;
    const int oy = blockIdx.y;            // == ot of the fragment
    const int obase = oy * 16;
    const int tid = threadIdx.x;
    const int c = tid & 127;
    const int hh = __builtin_amdgcn_readfirstlane(tid >> 7);  // wave-uniform

    const float* posb = pos + b * CCH * 2;
    const float S = 4.487989505128276f;  // 2*pi/1.4

    float accs[8];
#pragma unroll
    for (int k = 0; k < 8; ++k) accs[k] = 0.f;

#pragma unroll 1
    for (int cc = 0; cc < NIJ; cc += IJ_CHUNK) {
#pragma unroll 1
        for (int it = 0; it < (IJ_CHUNK * CCH) / 256; ++it) {
            int idx = it * 256 + tid;
            int ec = idx & 127;
            int ijl = idx >> 7;
            int ij = cc + ijl;
            int i = ij / NFREQ;
            int j = ij - i * NFREQ;
            float px = posb[2 * ec] + 0.2f;
            float py = posb[2 * ec + 1] + 0.2f;
            float ang = px * (S * (float)i) + py * (S * (float)j);
            float sv, cv;
            __sincosf(ang, &sv, &cv);
            cos_s[ijl * EMB_LD + ec] = cv;
            sin_s[ijl * EMB_LD + ec] = sv;
        }
        __syncthreads();
#pragma unroll 4
        for (int ijl = 0; ijl < IJ_CHUNK; ++ijl) {
            float cv = cos_s[ijl * EMB_LD + c];
            float sv = sin_s[ijl * EMB_LD + c];
            const float* hrow = heads + (size_t)(obase + hh * 8) * DD + (cc + ijl);
#pragma unroll
            for (int k = 0; k < 8; ++k) {
                accs[k] = fmaf(cv, hrow[k * DD], fmaf(sv, hrow[k * DD + NIJ], accs[k]));
            }
        }
        __syncthreads();
    }

    // scores -> LDS [16][129]
    float* sc = smem;
#pragma unroll
    for (int k = 0; k < 8; ++k) {
        sc[(hh * 8 + k) * EMB_LD + c] = accs[k];
    }
    __syncthreads();

    float* red  = smem + 16 * EMB_LD;
    float* red2 = red + 256;
    const int o16 = tid >> 4;
    const int part = tid & 15;
    const float* srow = sc + o16 * EMB_LD + part * 8;

    float m = -1e30f;
#pragma unroll
    for (int j = 0; j < 8; ++j) m = fmaxf(m, srow[j]);
    red[o16 * 16 + part] = m;
    __syncthreads();
    float M = red[o16 * 16];
#pragma unroll
    for (int p = 1; p < 16; ++p) M = fmaxf(M, red[o16 * 16 + p]);

    float ev[8];
    float s = 0.f;
#pragma unroll
    for (int j = 0; j < 8; ++j) { ev[j] = __expf(srow[j] - M); s += ev[j]; }
    red2[o16 * 16 + part] = s;
    __syncthreads();
    float Sum = 0.f;
#pragma unroll
    for (int p = 0; p < 16; ++p) Sum += red2[o16 * 16 + p];
    float inv = 1.f / Sum;

    v8h h;
#pragma unroll
    for (int j = 0; j < 8; ++j) h[j] = (_Float16)(ev[j] * inv);
    union { uint4 u; v8h v; } u;
    u.v = h;
    const int kc = part >> 2;
    const int lane = (part & 3) * 16 + o16;
    fragH[((b * 4 + kc) * 4 + oy) * 64 + lane] = u.u;
}

// ---------------- K2: R11 structure + NON-TEMPORAL output stores ----------------
// Mechanism (R13 evidence): timed replays have NO fills between them; working
// set eeg(134MB)+out(67MB) = 201MB < 256MB L3, yet timed k2 runs at the
// HBM-cold rate (53us) not the measured L3-hot rate (25us, R13 rep2) -> the
// 67MB/replay of dirty out lines (never read back) are evicting eeg from L3.
// Fix: 'nt' stores for out -> no L3 allocation/dirty pressure -> eeg stays
// L3-resident across replays. Loads stay cacheable on purpose.
// RULE #20: every acc[][] loop fully unrolled.
__global__ __launch_bounds__(256) void k2_mfma(const float* __restrict__ eeg,
                                               const uint4* __restrict__ fragH,
                                               float* __restrict__ out) {
    const int b = blockIdx.y;
    const int t0 = blockIdx.x * 256;
    const int lane = threadIdx.x & 63;
    const int wv = __builtin_amdgcn_readfirstlane(threadIdx.x >> 6);
    const int r16 = lane & 15;
    const int kq = lane >> 4;

    const float* ebase = eeg + ((size_t)b * TT + t0 + wv * 64) * CCH;

    f32x4 acc[4][4];
#pragma unroll
    for (int tt = 0; tt < 4; ++tt)
#pragma unroll
        for (int ot = 0; ot < 4; ++ot)
            acc[tt][ot] = (f32x4){0.f, 0.f, 0.f, 0.f};

#pragma unroll 1
    for (int kc = 0; kc < 4; ++kc) {
        const uint4* fh = fragH + (size_t)((b * 4 + kc) * 4) * 64 + lane;
        v8h bw[4];
#pragma unroll
        for (int ot = 0; ot < 4; ++ot) {
            union { uint4 u; v8h v; } u;
            u.u = fh[ot * 64];
            bw[ot] = u.v;
        }
#pragma unroll
        for (int tt = 0; tt < 4; ++tt) {
            const float* ap = ebase + (size_t)(tt * 16 + r16) * CCH + kc * 32 + kq * 8;
            float4 v0 = *(const float4*)ap;
            float4 v1 = *(const float4*)(ap + 4);
            v8h eh;
            eh[0] = (_Float16)v0.x; eh[1] = (_Float16)v0.y;
            eh[2] = (_Float16)v0.z; eh[3] = (_Float16)v0.w;
            eh[4] = (_Float16)v1.x; eh[5] = (_Float16)v1.y;
            eh[6] = (_Float16)v1.z; eh[7] = (_Float16)v1.w;
#pragma unroll
            for (int ot = 0; ot < 4; ++ot) {
                acc[tt][ot] = __builtin_amdgcn_mfma_f32_16x16x32_f16(bw[ot], eh, acc[tt][ot], 0, 0, 0);
            }
        }
    }

    // epilogue: lane holds D[o_local = kq*4 + reg][t_local = r16] per (tt,ot)
    // -> one NON-TEMPORAL float4 store per (tt,ot)
    const size_t orow0 = (size_t)b * TT + t0 + wv * 64;
#pragma unroll
    for (int tt = 0; tt < 4; ++tt) {
        float* dst_row = out + (orow0 + tt * 16 + r16) * OO + kq * 4;
#pragma unroll
        for (int ot = 0; ot < 4; ++ot) {
            __builtin_nontemporal_store(acc[tt][ot], (f32x4*)(dst_row + ot * 16));
        }
    }
}

extern "C" void kernel_launch(void* const* d_in, const int* in_sizes, int n_in,
                              void* d_out, int out_size, void* d_ws, size_t ws_size,
                              hipStream_t stream) {
    const float* eeg   = (const float*)d_in[0];   // [B,T,C]
    const float* pos   = (const float*)d_in[1];   // [B,C,2]
    const float* heads = (const float*)d_in[2];   // [O,D]
    float* out = (float*)d_out;                   // [B,T,O]

    uint4* fragH = (uint4*)d_ws;                  // 32*4*4*64*16 = 524288 B

    k1f_frag<<<dim3(BB, 4), 256, 0, stream>>>(pos, heads, fragH);
    k2_mfma<<<dim3(TT / 256, BB), 256, 0, stream>>>(eeg, fragH, out);
}

// Round 16
// 57.529 us; speedup vs baseline: 1.0984x; 1.0984x over previous
//
#include <hip/hip_runtime.h>
#include <math.h>

#define BB 32
#define TT 8192
#define CCH 128
#define OO 64
#define DD 288
#define NFREQ 12
#define NIJ 144

typedef _Float16 v8h __attribute__((ext_vector_type(8)));
typedef float f32x4 __attribute__((ext_vector_type(4)));

// ---------------- K1f: fourier emb + scores + softmax -> fragH, fused ----------------
// (R11 best configuration, restored. 57.2 us measured.)
#define IJ_CHUNK 36
#define EMB_LD 129

__global__ __launch_bounds__(256) void k1f_frag(const float* __restrict__ pos,
                                                const float* __restrict__ heads,
                                                uint4* __restrict__ fragH) {
    __shared__ float smem[2 * IJ_CHUNK * EMB_LD];   // 9288 floats = 37 KB
    float* cos_s = smem;
    float* sin_s = smem + IJ_CHUNK * EMB_LD;

    const int b = blockIdx.x;
    const int oy = blockIdx.y;            // == ot of the fragment
    const int obase = oy * 16;
    const int tid = threadIdx.x;
    const int c = tid & 127;
    const int hh = __builtin_amdgcn_readfirstlane(tid >> 7);  // wave-uniform

    const float* posb = pos + b * CCH * 2;
    const float S = 4.487989505128276f;  // 2*pi/1.4

    float accs[8];
#pragma unroll
    for (int k = 0; k < 8; ++k) accs[k] = 0.f;

#pragma unroll 1
    for (int cc = 0; cc < NIJ; cc += IJ_CHUNK) {
#pragma unroll 1
        for (int it = 0; it < (IJ_CHUNK * CCH) / 256; ++it) {
            int idx = it * 256 + tid;
            int ec = idx & 127;
            int ijl = idx >> 7;
            int ij = cc + ijl;
            int i = ij / NFREQ;
            int j = ij - i * NFREQ;
            float px = posb[2 * ec] + 0.2f;
            float py = posb[2 * ec + 1] + 0.2f;
            float ang = px * (S * (float)i) + py * (S * (float)j);
            float sv, cv;
            __sincosf(ang, &sv, &cv);
            cos_s[ijl * EMB_LD + ec] = cv;
            sin_s[ijl * EMB_LD + ec] = sv;
        }
        __syncthreads();
#pragma unroll 4
        for (int ijl = 0; ijl < IJ_CHUNK; ++ijl) {
            float cv = cos_s[ijl * EMB_LD + c];
            float sv = sin_s[ijl * EMB_LD + c];
            const float* hrow = heads + (size_t)(obase + hh * 8) * DD + (cc + ijl);
#pragma unroll
            for (int k = 0; k < 8; ++k) {
                accs[k] = fmaf(cv, hrow[k * DD], fmaf(sv, hrow[k * DD + NIJ], accs[k]));
            }
        }
        __syncthreads();
    }

    // scores -> LDS [16][129]
    float* sc = smem;
#pragma unroll
    for (int k = 0; k < 8; ++k) {
        sc[(hh * 8 + k) * EMB_LD + c] = accs[k];
    }
    __syncthreads();

    float* red  = smem + 16 * EMB_LD;
    float* red2 = red + 256;
    const int o16 = tid >> 4;
    const int part = tid & 15;
    const float* srow = sc + o16 * EMB_LD + part * 8;

    float m = -1e30f;
#pragma unroll
    for (int j = 0; j < 8; ++j) m = fmaxf(m, srow[j]);
    red[o16 * 16 + part] = m;
    __syncthreads();
    float M = red[o16 * 16];
#pragma unroll
    for (int p = 1; p < 16; ++p) M = fmaxf(M, red[o16 * 16 + p]);

    float ev[8];
    float s = 0.f;
#pragma unroll
    for (int j = 0; j < 8; ++j) { ev[j] = __expf(srow[j] - M); s += ev[j]; }
    red2[o16 * 16 + part] = s;
    __syncthreads();
    float Sum = 0.f;
#pragma unroll
    for (int p = 0; p < 16; ++p) Sum += red2[o16 * 16 + p];
    float inv = 1.f / Sum;

    v8h h;
#pragma unroll
    for (int j = 0; j < 8; ++j) h[j] = (_Float16)(ev[j] * inv);
    union { uint4 u; v8h v; } u;
    u.v = h;
    const int kc = part >> 2;
    const int lane = (part & 3) * 16 + o16;
    fragH[((b * 4 + kc) * 4 + oy) * 64 + lane] = u.u;
}

// ---------------- K2: out[b,t,o] = sum_c eeg[b,t,c] * w[b,o,c] via fp16 MFMA ----
// R11 best structure (57.2 us): 256 thr = 4 waves; wave owns 64 t-rows (4 tiles
// of 16), direct global loads. mfma(A=w_frag, B=eeg_frag):
// D[row=o_local=kq*4+reg][col=t_local=r16] -> float4 cacheable stores.
// Empirical wall (R13 PMC): bytes exact (FETCH=135MB, WRITE=64MB), all pipes
// idle (VALU 12%, MFMA 4%), L3-hot 2.1x faster -> limited by delivered memory
// rate for the 2:1 R/W mix; insensitive to granularity/occupancy/contiguity/
// pipelining/ordering/cache-policy (R7-R15).
// RULE #20: every acc[][] loop fully unrolled.
__global__ __launch_bounds__(256) void k2_mfma(const float* __restrict__ eeg,
                                               const uint4* __restrict__ fragH,
                                               float* __restrict__ out) {
    const int b = blockIdx.y;
    const int t0 = blockIdx.x * 256;
    const int lane = threadIdx.x & 63;
    const int wv = __builtin_amdgcn_readfirstlane(threadIdx.x >> 6);
    const int r16 = lane & 15;
    const int kq = lane >> 4;

    const float* ebase = eeg + ((size_t)b * TT + t0 + wv * 64) * CCH;

    f32x4 acc[4][4];
#pragma unroll
    for (int tt = 0; tt < 4; ++tt)
#pragma unroll
        for (int ot = 0; ot < 4; ++ot)
            acc[tt][ot] = (f32x4){0.f, 0.f, 0.f, 0.f};

#pragma unroll 1
    for (int kc = 0; kc < 4; ++kc) {
        const uint4* fh = fragH + (size_t)((b * 4 + kc) * 4) * 64 + lane;
        v8h bw[4];
#pragma unroll
        for (int ot = 0; ot < 4; ++ot) {
            union { uint4 u; v8h v; } u;
            u.u = fh[ot * 64];
            bw[ot] = u.v;
        }
#pragma unroll
        for (int tt = 0; tt < 4; ++tt) {
            const float* ap = ebase + (size_t)(tt * 16 + r16) * CCH + kc * 32 + kq * 8;
            float4 v0 = *(const float4*)ap;
            float4 v1 = *(const float4*)(ap + 4);
            v8h eh;
            eh[0] = (_Float16)v0.x; eh[1] = (_Float16)v0.y;
            eh[2] = (_Float16)v0.z; eh[3] = (_Float16)v0.w;
            eh[4] = (_Float16)v1.x; eh[5] = (_Float16)v1.y;
            eh[6] = (_Float16)v1.z; eh[7] = (_Float16)v1.w;
#pragma unroll
            for (int ot = 0; ot < 4; ++ot) {
                acc[tt][ot] = __builtin_amdgcn_mfma_f32_16x16x32_f16(bw[ot], eh, acc[tt][ot], 0, 0, 0);
            }
        }
    }

    // epilogue: lane holds D[o_local = kq*4 + reg][t_local = r16] per (tt,ot)
    const size_t orow0 = (size_t)b * TT + t0 + wv * 64;
#pragma unroll
    for (int tt = 0; tt < 4; ++tt) {
        float* dst_row = out + (orow0 + tt * 16 + r16) * OO + kq * 4;
#pragma unroll
        for (int ot = 0; ot < 4; ++ot) {
            float4 v;
            v.x = acc[tt][ot][0];
            v.y = acc[tt][ot][1];
            v.z = acc[tt][ot][2];
            v.w = acc[tt][ot][3];
            *(float4*)(dst_row + ot * 16) = v;
        }
    }
}

extern "C" void kernel_launch(void* const* d_in, const int* in_sizes, int n_in,
                              void* d_out, int out_size, void* d_ws, size_t ws_size,
                              hipStream_t stream) {
    const float* eeg   = (const float*)d_in[0];   // [B,T,C]
    const float* pos   = (const float*)d_in[1];   // [B,C,2]
    const float* heads = (const float*)d_in[2];   // [O,D]
    float* out = (float*)d_out;                   // [B,T,O]

    uint4* fragH = (uint4*)d_ws;                  // 32*4*4*64*16 = 524288 B

    k1f_frag<<<dim3(BB, 4), 256, 0, stream>>>(pos, heads, fragH);
    k2_mfma<<<dim3(TT / 256, BB), 256, 0, stream>>>(eeg, fragH, out);
}